// Round 1
// 207.356 us; speedup vs baseline: 1.0049x; 1.0049x over previous
//
#include <hip/hip_runtime.h>
#include <hip/hip_bf16.h>

#define HID 256
#define NROWS 2048
#define NITER 8
#define GRID (NROWS / NITER)   // 256 persistent blocks = 1 per CU
#define PITCH 264              // bf16 row pitch: 256 + 8 pad
#define TILE_F (64 * 256)      // floats per row-tile (64 words x 256 hid)

typedef __attribute__((ext_vector_type(8))) short short8;   // 8 bf16 (MFMA A/B frag)
typedef __attribute__((ext_vector_type(4))) float float4v;
typedef __attribute__((ext_vector_type(4))) unsigned int uint4v;

__device__ __forceinline__ float bf2f(unsigned short u) {
    return __uint_as_float(((unsigned int)u) << 16);
}

__device__ __forceinline__ unsigned int pk_bf16(float a, float b) {
    __hip_bfloat162 p = __float22bfloat162_rn(float2{a, b});  // v_cvt_pk_bf16_f32
    return *(unsigned int*)&p;
}

// Raw barrier: drains LDS ops only. Unlike __syncthreads it does NOT emit
// vmcnt(0), so the in-flight global loads for tile t+1 survive the barrier
// (m201/m218 template idiom). sched_barrier(0) brackets pin ordering (rule 18).
__device__ __forceinline__ void bar_sync() {
    __builtin_amdgcn_sched_barrier(0);
    asm volatile("s_waitcnt lgkmcnt(0)");
    __builtin_amdgcn_s_barrier();
    __builtin_amdgcn_sched_barrier(0);
}

// sum across each 16-lane DPP row (VALU pipe, no LDS)
__device__ __forceinline__ float row16_sum(float v) {
    float t;
    t = __builtin_bit_cast(float, __builtin_amdgcn_update_dpp(
            0, __builtin_bit_cast(int, v), 0xB1, 0xf, 0xf, true));  // quad_perm(1,0,3,2)
    v += t;
    t = __builtin_bit_cast(float, __builtin_amdgcn_update_dpp(
            0, __builtin_bit_cast(int, v), 0x4E, 0xf, 0xf, true));  // quad_perm(2,3,0,1)
    v += t;
    t = __builtin_bit_cast(float, __builtin_amdgcn_update_dpp(
            0, __builtin_bit_cast(int, v), 0x124, 0xf, 0xf, true)); // row_ror:4
    v += t;
    t = __builtin_bit_cast(float, __builtin_amdgcn_update_dpp(
            0, __builtin_bit_cast(int, v), 0x128, 0xf, 0xf, true)); // row_ror:8
    v += t;
    return v;
}

// Persistent pipelined kernel, reg-staged deep prefetch:
//   regs R hold tile t+1 (issued one full iteration early, ~6400cy of cover)
//   xs[2] double-buffered bf16 tiles; only lgkm barriers inside the loop.
__global__ __launch_bounds__(512, 2) void attend_fused(
    const float* __restrict__ x, const float* __restrict__ W,
    const float* __restrict__ bias, const float* __restrict__ ctx,
    float* __restrict__ out)
{
    __shared__ unsigned short xs[2][64 * PITCH];   // 66 KB double-buffered tile
    __shared__ float wsum[8][64];
    __shared__ float rinv[64];

    const int tid  = threadIdx.x;
    const int wave = tid >> 6;    // 0..7
    const int lane = tid & 63;
    const int q    = lane >> 4;   // quad 0..3
    const int c    = lane & 15;
    const int obase = wave * 32;  // wave's 32 output cols; lane pair: obase+2c+{0,1}
    const int n0 = blockIdx.x * NITER;

    // ---- issue tile-0 loads first so the HBM stream starts immediately ----
    float4v R[8];                 // 32 VGPR staging block (64 KB per block)
    {
        const float4v* xv = (const float4v*)(x + (size_t)n0 * TILE_F);
#pragma unroll
        for (int i = 0; i < 8; ++i) R[i] = xv[tid + 512 * i];
    }

    // ---- loop invariants (cover tile-0 latency): B frags straight from W ----
    // e^(c*tanh(y)) = e^c * 2^(m2/(E+1)),  E = 2^(2y*log2e), m2 = -2c*log2e
    float bb[2], m2[2], ec[2];
    short8 bfrag[8][2];           // 64 VGPR: whole B tile for this wave
#pragma unroll
    for (int nt = 0; nt < 2; ++nt) {
        const int o = obase + 2 * c + nt;
        bb[nt] = bias[o];
        const float cv = ctx[o];
        m2[nt] = cv * -2.8853900817779268f;
        ec[nt] = __builtin_amdgcn_exp2f(cv * 1.4426950408889634f);
        const float* wr = W + (size_t)o * 256 + q * 8;
#pragma unroll
        for (int kt = 0; kt < 8; ++kt) {
            float4v w0 = *(const float4v*)(wr + kt * 32);
            float4v w1 = *(const float4v*)(wr + kt * 32 + 4);
            uint4v u = { pk_bf16(w0.x, w0.y), pk_bf16(w0.z, w0.w),
                         pk_bf16(w1.x, w1.y), pk_bf16(w1.z, w1.w) };
            bfrag[kt][nt] = __builtin_bit_cast(short8, u);
        }
    }

    // ---- cvt tile 0 -> xs[0]; issue tile-1 loads ----
#pragma unroll
    for (int i = 0; i < 8; ++i) {
        const int chunk = tid + 512 * i;
        const int r = chunk >> 6, col4 = (chunk & 63) * 4;
        uint2 u;
        u.x = pk_bf16(R[i].x, R[i].y);
        u.y = pk_bf16(R[i].z, R[i].w);
        *(uint2*)&xs[0][r * PITCH + col4] = u;
    }
    {
        const float4v* xv = (const float4v*)(x + (size_t)(n0 + 1) * TILE_F);
#pragma unroll
        for (int i = 0; i < 8; ++i) R[i] = xv[tid + 512 * i];
    }
    bar_sync();

    int cur = 0;
#pragma unroll 1
    for (int it = 0; it < NITER; ++it) {
        const unsigned short* xsc = xs[cur];

        // ---- GEMM: 64 rows x 32 cols per wave; zero vmem waits in here ----
        float4v acc[4][2];
#pragma unroll
        for (int mt = 0; mt < 4; ++mt)
#pragma unroll
            for (int nt = 0; nt < 2; ++nt)
                acc[mt][nt] = (float4v){0.f, 0.f, 0.f, 0.f};

#pragma unroll
        for (int kt = 0; kt < 8; ++kt) {
            short8 a[4];
#pragma unroll
            for (int mt = 0; mt < 4; ++mt)
                a[mt] = *(const short8*)&xsc[(mt * 16 + c) * PITCH + kt * 32 + q * 8];
#pragma unroll
            for (int nt = 0; nt < 2; ++nt)
#pragma unroll
                for (int mt = 0; mt < 4; ++mt)
                    acc[mt][nt] = __builtin_amdgcn_mfma_f32_16x16x32_bf16(
                        a[mt], bfrag[kt][nt], acc[mt][nt], 0, 0, 0);
        }

        // ---- epilogue: fused e = e^c * 2^(m2/(E+1)); row sums via DPP ----
        // D layout: row = 16*mt + 4*q + r, col = obase + 2*c + nt
        float psum[4][4];
#pragma unroll
        for (int mt = 0; mt < 4; ++mt)
#pragma unroll
            for (int r = 0; r < 4; ++r)
                psum[mt][r] = 0.f;

#pragma unroll
        for (int nt = 0; nt < 2; ++nt) {
#pragma unroll
            for (int mt = 0; mt < 4; ++mt) {
#pragma unroll
                for (int r = 0; r < 4; ++r) {
                    const float y  = acc[mt][nt][r] + bb[nt];
                    const float E  = __builtin_amdgcn_exp2f(y * 2.8853900817779268f);
                    const float rd = __builtin_amdgcn_rcpf(E + 1.0f);
                    const float e  = ec[nt] * __builtin_amdgcn_exp2f(m2[nt] * rd);
                    acc[mt][nt][r] = e;
                    psum[mt][r] += e;
                }
            }
        }
#pragma unroll
        for (int mt = 0; mt < 4; ++mt)
#pragma unroll
            for (int r = 0; r < 4; ++r)
                psum[mt][r] = row16_sum(psum[mt][r]);
        if (c == 0) {
#pragma unroll
            for (int mt = 0; mt < 4; ++mt) {
                float4v p = {psum[mt][0], psum[mt][1], psum[mt][2], psum[mt][3]};
                *(float4v*)&wsum[wave][mt * 16 + q * 4] = p;
            }
        }
        bar_sync();
        if (tid < 64) {
            const float t = wsum[0][tid] + wsum[1][tid] + wsum[2][tid] + wsum[3][tid]
                          + wsum[4][tid] + wsum[5][tid] + wsum[6][tid] + wsum[7][tid];
            rinv[tid] = __builtin_amdgcn_rcpf(t);
        }
        bar_sync();

        // ---- out[h] = sum_w x[w][h]*e[w][h]*rinv[w]; paired-col b32 reads ----
        float ri[4][4];
#pragma unroll
        for (int mt = 0; mt < 4; ++mt)
#pragma unroll
            for (int r = 0; r < 4; ++r)
                ri[mt][r] = rinv[mt * 16 + q * 4 + r];

        float outp[2] = {0.f, 0.f};
#pragma unroll
        for (int mt = 0; mt < 4; ++mt) {
#pragma unroll
            for (int r = 0; r < 4; ++r) {
                const int w = mt * 16 + q * 4 + r;
                unsigned int pair = *(const unsigned int*)&xsc[w * PITCH + obase + 2 * c];
                const float wgt = ri[mt][r];
                outp[0] += bf2f((unsigned short)pair)         * (acc[mt][0][r] * wgt);
                outp[1] += bf2f((unsigned short)(pair >> 16)) * (acc[mt][1][r] * wgt);
            }
        }
#pragma unroll
        for (int nt = 0; nt < 2; ++nt) {
            float v = outp[nt];
            v += __shfl_xor(v, 16);   // combine the 4 quads' disjoint w-ranges
            v += __shfl_xor(v, 32);
            outp[nt] = v;
        }
        if (q == 0)
            *(float2*)&out[(size_t)(n0 + it) * HID + obase + 2 * c] = float2{outp[0], outp[1]};

        // ---- stage tile it+1 (regs -> xs[cur^1]); issue loads for tile it+2.
        //      The vmcnt waits for R land here, covered by everything above. ----
        if (it + 1 < NITER) {
            unsigned short* xsn = (unsigned short*)xs[cur ^ 1];
#pragma unroll
            for (int i = 0; i < 8; ++i) {
                const int chunk = tid + 512 * i;
                const int r = chunk >> 6, col4 = (chunk & 63) * 4;
                uint2 u;
                u.x = pk_bf16(R[i].x, R[i].y);
                u.y = pk_bf16(R[i].z, R[i].w);
                *(uint2*)&xsn[r * PITCH + col4] = u;
            }
            if (it + 2 < NITER) {
                const float4v* xv = (const float4v*)(x + (size_t)(n0 + it + 2) * TILE_F);
#pragma unroll
                for (int i = 0; i < 8; ++i) R[i] = xv[tid + 512 * i];
            }
        }
        bar_sync();
        cur ^= 1;
    }
}

extern "C" void kernel_launch(void* const* d_in, const int* in_sizes, int n_in,
                              void* d_out, int out_size, void* d_ws, size_t ws_size,
                              hipStream_t stream) {
    const float* x    = (const float*)d_in[0];   // [2048, 64, 256] f32
    const float* W    = (const float*)d_in[1];   // [256, 256] f32
    const float* bias = (const float*)d_in[2];   // [256]
    const float* ctx  = (const float*)d_in[3];   // [256]
    (void)in_sizes; (void)n_in; (void)d_ws; (void)ws_size;

    attend_fused<<<GRID, 512, 0, stream>>>(x, W, bias, ctx, (float*)d_out);
}